// Round 4
// baseline (669.851 us; speedup 1.0000x reference)
//
#include <hip/hip_runtime.h>
#include <hip/hip_bf16.h>
#include <math.h>

// Problem constants (from reference)
#define D_BINS 59
#define CTX    80
#define O_TOT  139      // D_BINS + CTX
#define K_CIN  256
#define PIXELS 704      // 16*44
#define BNPAIR 24       // B*N = 4*6
#define BEVHW  16384    // 128*128
#define NBATCH 4
#define NPOINT (BNPAIR * D_BINS * PIXELS)   // 996,864
#define PPB    (D_BINS * PIXELS)            // 41,536 points per (b,n)
#define PPBAT  (6 * PPB)                    // 249,216 points per batch

// Coarse binning: tile = 8 rows x 16 cols of BEV cells -> 128 cells/tile,
// 128 tiles/batch, 512 buckets total. ~1947 points/bucket.
#define NTILE   128
#define NBUCKET (NBATCH * NTILE)            // 512
#define TCELLS  128                         // cells per tile

// Workspace layout (float/int units, all offsets even -> 8B aligned):
#define XDEPTH_OFF 0
#define CTX_OFF    (XDEPTH_OFF + NPOINT)
#define COUNTS_OFF (CTX_OFF + BNPAIR * PIXELS * CTX)
#define OFFS_OFF   (COUNTS_OFF + NBUCKET)
#define FILLP_OFF  (OFFS_OFF + NBUCKET)        // padded: 16 ints per bucket
#define PLIST_OFF  (FILLP_OFF + NBUCKET * 16)

// ---------------------------------------------------------------------------
// Kernel 1: per-(b,n) GEMM  x[o][pix] = sum_k w[o][k]*img[k][pix] + bias[o]
// 64 outputs x 128 pixels tile, K-step 16, 4x8 register micro-tile.
// ---------------------------------------------------------------------------
__global__ __launch_bounds__(256) void gemm_kernel(
    const float* __restrict__ img,    // (BNPAIR, 256, 704)
    const float* __restrict__ w,      // (139, 256)
    const float* __restrict__ bias,   // (139)
    float* __restrict__ xdepth,
    float* __restrict__ ctx)
{
    __shared__ float As[16][64];    // [k][o_local]
    __shared__ float Bs[16][128];   // [k][p_local]

    const int tid = threadIdx.x;
    const int tx  = tid & 15;
    const int ty  = tid >> 4;
    const int bn  = blockIdx.z;
    const int o0  = blockIdx.y * 64;
    const int p0  = blockIdx.x * 128;

    const float* imgbn = img + (size_t)bn * K_CIN * PIXELS;

    float acc[4][8];
#pragma unroll
    for (int i = 0; i < 4; ++i)
#pragma unroll
        for (int j = 0; j < 8; ++j) acc[i][j] = 0.f;

    const int a_ol = tid >> 2;          // 0..63
    const int a_kc = (tid & 3) * 4;     // 0,4,8,12

    for (int kt = 0; kt < K_CIN; kt += 16) {
        {
            int o = o0 + a_ol;
            float4 v = make_float4(0.f, 0.f, 0.f, 0.f);
            if (o < O_TOT) v = *(const float4*)&w[(size_t)o * K_CIN + kt + a_kc];
            As[a_kc + 0][a_ol] = v.x;
            As[a_kc + 1][a_ol] = v.y;
            As[a_kc + 2][a_ol] = v.z;
            As[a_kc + 3][a_ol] = v.w;
        }
#pragma unroll
        for (int r = 0; r < 2; ++r) {
            int e   = tid + 256 * r;
            int k_l = e >> 5;
            int p4  = (e & 31) * 4;
            int pg  = p0 + p4;
            float4 v = make_float4(0.f, 0.f, 0.f, 0.f);
            if (pg < PIXELS) v = *(const float4*)&imgbn[(size_t)(kt + k_l) * PIXELS + pg];
            *(float4*)&Bs[k_l][p4] = v;
        }
        __syncthreads();

#pragma unroll
        for (int kk = 0; kk < 16; ++kk) {
            float4 a  = *(const float4*)&As[kk][ty * 4];
            float4 b0 = *(const float4*)&Bs[kk][tx * 8];
            float4 b1 = *(const float4*)&Bs[kk][tx * 8 + 4];
            const float av[4] = {a.x, a.y, a.z, a.w};
            const float bv[8] = {b0.x, b0.y, b0.z, b0.w, b1.x, b1.y, b1.z, b1.w};
#pragma unroll
            for (int i = 0; i < 4; ++i)
#pragma unroll
                for (int j = 0; j < 8; ++j)
                    acc[i][j] += av[i] * bv[j];
        }
        __syncthreads();
    }

    const bool full_p = (p0 + 127) < PIXELS;
#pragma unroll
    for (int i = 0; i < 4; ++i) {
        const int o = o0 + ty * 4 + i;
        if (o >= O_TOT) continue;
        const float bv = bias[o];
        if (o < D_BINS) {
            float* dst = xdepth + ((size_t)bn * D_BINS + o) * PIXELS + p0 + tx * 8;
#pragma unroll
            for (int j = 0; j < 8; ++j) {
                if (full_p || (p0 + tx * 8 + j < PIXELS)) dst[j] = acc[i][j] + bv;
            }
        } else {
            const int c = o - D_BINS;
            float* dst = ctx + ((size_t)bn * PIXELS + p0 + tx * 8) * CTX + c;
#pragma unroll
            for (int j = 0; j < 8; ++j) {
                if (full_p || (p0 + tx * 8 + j < PIXELS)) dst[(size_t)j * CTX] = acc[i][j] + bv;
            }
        }
    }
}

// ---------------------------------------------------------------------------
// Kernel 2: softmax over 59 depth bins, in place. Thread-per-pixel,
// fully coalesced, values in registers.
// ---------------------------------------------------------------------------
__global__ __launch_bounds__(256) void softmax_kernel(float* __restrict__ xdepth)
{
    const int pix = blockIdx.x * 256 + threadIdx.x;   // < 16896 exactly
    const int bn  = pix / PIXELS;
    const int pp  = pix - bn * PIXELS;
    float* base = xdepth + ((size_t)bn * D_BINS) * PIXELS + pp;

    float v[D_BINS];
    float m = -INFINITY;
#pragma unroll
    for (int d = 0; d < D_BINS; ++d) {
        v[d] = base[(size_t)d * PIXELS];
        m = fmaxf(m, v[d]);
    }
    float s = 0.f;
#pragma unroll
    for (int d = 0; d < D_BINS; ++d) {
        v[d] = __expf(v[d] - m);
        s += v[d];
    }
    const float inv = 1.f / s;
#pragma unroll
    for (int d = 0; d < D_BINS; ++d)
        base[(size_t)d * PIXELS] = v[d] * inv;
}

// ---------------------------------------------------------------------------
// Kernel 3: histogram over 512 (b,tile) buckets via LDS, then flush.
// 244 blocks x 1024 threads, 4 points/thread.
// ---------------------------------------------------------------------------
__global__ __launch_bounds__(1024) void hist_kernel(
    const int* __restrict__ geom, int* __restrict__ counts)
{
    __shared__ int h[NBUCKET];
    const int tid = threadIdx.x;
    if (tid < NBUCKET) h[tid] = 0;
    __syncthreads();

    const int base = blockIdx.x * 4096;
#pragma unroll
    for (int r = 0; r < 4; ++r) {
        const int pt = base + r * 1024 + tid;
        if (pt < NPOINT) {
            const int g0 = geom[2 * (size_t)pt];
            const int g1 = geom[2 * (size_t)pt + 1];
            const int b  = pt / PPBAT;
            atomicAdd(&h[b * NTILE + (g0 >> 3) * 8 + (g1 >> 4)], 1);
        }
    }
    __syncthreads();
    if (tid < NBUCKET && h[tid]) atomicAdd(&counts[tid], h[tid]);
}

// ---------------------------------------------------------------------------
// Kernel 4: exclusive scan over 512 bucket counts; init padded fill cursors.
// ---------------------------------------------------------------------------
__global__ __launch_bounds__(NBUCKET) void scan_kernel(
    const int* __restrict__ counts, int* __restrict__ offs, int* __restrict__ fillp)
{
    __shared__ int s[NBUCKET];
    const int tid = threadIdx.x;
    const int v   = counts[tid];
    s[tid] = v;
    __syncthreads();
#pragma unroll
    for (int off = 1; off < NBUCKET; off <<= 1) {
        int t = (tid >= off) ? s[tid - off] : 0;
        __syncthreads();
        s[tid] += t;
        __syncthreads();
    }
    const int e = s[tid] - v;
    offs[tid] = e;
    fillp[tid * 16] = e;
}

// ---------------------------------------------------------------------------
// Kernel 5: fill per-bucket point lists. Appends within a bucket hit
// consecutive positions -> L2 write-combining (vs R3's 64K-bucket scatter).
// entry = { depth_bits, (ctx_offset << 7) | cell_in_tile }
// ---------------------------------------------------------------------------
__global__ __launch_bounds__(256) void fill_kernel(
    const int*   __restrict__ geom,
    const float* __restrict__ xdepth,
    int*         __restrict__ fillp,
    uint2*       __restrict__ plist)
{
    const int pt  = blockIdx.x * 256 + threadIdx.x;       // < NPOINT exactly
    const int g0  = geom[2 * (size_t)pt];
    const int g1  = geom[2 * (size_t)pt + 1];
    const int bnd = pt / PIXELS;          // bn*59 + d
    const int pp  = pt - bnd * PIXELS;
    const int bn  = bnd / D_BINS;
    const int b   = bn / 6;
    const float dep = xdepth[pt];

    const int bucket = b * NTILE + (g0 >> 3) * 8 + (g1 >> 4);
    const int cell   = (g0 & 7) * 16 + (g1 & 15);          // 0..127
    const unsigned y = ((unsigned)((bn * PIXELS + pp) * CTX) << 7) | (unsigned)cell;

    const int pos = atomicAdd(&fillp[bucket * 16], 1);
    plist[pos] = make_uint2(__float_as_uint(dep), y);
}

// ---------------------------------------------------------------------------
// Kernel 6: gather. One block per bucket (512 blocks x 1024 thr = 16 waves).
// LDS accumulator tile: 128 cells x 80 ch (pad 81 -> conflict-free).
// Per point: broadcast 8B entry read + coalesced 320B ctx read + ds_add_f32.
// Epilogue: full 64B-line writes into (B, C, H, W).
// ---------------------------------------------------------------------------
__global__ __launch_bounds__(1024) void gather_kernel(
    const uint2* __restrict__ plist,
    const int*   __restrict__ offs,
    const int*   __restrict__ counts,
    const float* __restrict__ ctx,
    float*       __restrict__ out)
{
    __shared__ float sacc[TCELLS][CTX + 1];   // 128 x 81 floats = 41.5 KB

    const int tid  = threadIdx.x;
    const int wv   = tid >> 6;      // 0..15
    const int lane = tid & 63;

    // zero accumulator: 128*81 = 10368 floats
    for (int i = tid; i < TCELLS * (CTX + 1); i += 1024)
        ((float*)sacc)[i] = 0.f;
    __syncthreads();

    const int bucket = blockIdx.x;
    const int start  = offs[bucket];
    const int cnt    = counts[bucket];

    int i = wv * 2;
    for (; i + 1 < cnt; i += 32) {
        const uint2 p0 = plist[start + i];
        const uint2 p1 = plist[start + i + 1];
        const float d0 = __uint_as_float(p0.x);
        const float d1 = __uint_as_float(p1.x);
        const int  c0i = (int)(p0.y >> 7);
        const int  c1i = (int)(p1.y >> 7);
        const int  e0  = (int)(p0.y & 127u);
        const int  e1  = (int)(p1.y & 127u);
        const float* c0 = ctx + c0i;
        const float* c1 = ctx + c1i;
        const float v0 = c0[lane];
        const float v1 = c1[lane];
        atomicAdd(&sacc[e0][lane], d0 * v0);
        atomicAdd(&sacc[e1][lane], d1 * v1);
        if (lane < 16) {
            atomicAdd(&sacc[e0][64 + lane], d0 * c0[64 + lane]);
            atomicAdd(&sacc[e1][64 + lane], d1 * c1[64 + lane]);
        }
    }
    if (i < cnt) {
        const uint2 pe = plist[start + i];
        const float dep = __uint_as_float(pe.x);
        const int  ci  = (int)(pe.y >> 7);
        const int  e   = (int)(pe.y & 127u);
        const float* cb = ctx + ci;
        atomicAdd(&sacc[e][lane], dep * cb[lane]);
        if (lane < 16) atomicAdd(&sacc[e][64 + lane], dep * cb[64 + lane]);
    }
    __syncthreads();

    // Epilogue: bucket -> (b, tile-row tr 0..15, tile-col tc 0..7)
    const int b  = bucket >> 7;
    const int tl = bucket & 127;
    const int tr = tl >> 3;
    const int tc = tl & 7;
    const int c  = tid >> 4;        // 0..63
    const int col= tid & 15;
#pragma unroll
    for (int cc = c; cc < CTX; cc += 64) {
#pragma unroll
        for (int r = 0; r < 8; ++r) {
            const int g0 = tr * 8 + r;
            const int g1 = tc * 16 + col;
            out[((size_t)(b * CTX + cc)) * BEVHW + g0 * 128 + g1] = sacc[r * 16 + col][cc];
        }
    }
}

extern "C" void kernel_launch(void* const* d_in, const int* in_sizes, int n_in,
                              void* d_out, int out_size, void* d_ws, size_t ws_size,
                              hipStream_t stream)
{
    const float* img  = (const float*)d_in[0];
    const float* w    = (const float*)d_in[4];
    const float* bias = (const float*)d_in[5];
    const int*   geom = (const int*)d_in[6];
    float*       out  = (float*)d_out;

    float* ws     = (float*)d_ws;
    float* xdepth = ws + XDEPTH_OFF;
    float* ctx    = ws + CTX_OFF;
    int*   counts = (int*)(ws + COUNTS_OFF);
    int*   offs   = (int*)(ws + OFFS_OFF);
    int*   fillp  = (int*)(ws + FILLP_OFF);
    uint2* plist  = (uint2*)(ws + PLIST_OFF);

    // bucket counters must start at zero (ws is poisoned 0xAA each call)
    hipMemsetAsync(counts, 0, NBUCKET * sizeof(int), stream);

    // 1. GEMM + bias -> depth logits (bn,d,pix) / transposed context (bn,pix,c)
    {
        dim3 grid(6, 3, BNPAIR);
        gemm_kernel<<<grid, 256, 0, stream>>>(img, w, bias, xdepth, ctx);
    }
    // 2. softmax over depth bins
    softmax_kernel<<<(BNPAIR * PIXELS) / 256, 256, 0, stream>>>(xdepth);

    // 3. coarse counting sort into 512 (b,tile) buckets
    hist_kernel<<<(NPOINT + 4095) / 4096, 1024, 0, stream>>>(geom, counts);
    scan_kernel<<<1, NBUCKET, 0, stream>>>(counts, offs, fillp);
    fill_kernel<<<NPOINT / 256, 256, 0, stream>>>(geom, xdepth, fillp, plist);

    // 4. gather per bucket: LDS tile accumulate, coalesced (B,C,H,W) writes
    gather_kernel<<<NBUCKET, 1024, 0, stream>>>(plist, offs, counts, ctx, out);
}

// Round 5
// 206.782 us; speedup vs baseline: 3.2394x; 3.2394x over previous
//
#include <hip/hip_runtime.h>
#include <hip/hip_bf16.h>
#include <math.h>

// Problem constants (from reference)
#define D_BINS 59
#define CTX    80
#define O_TOT  139      // D_BINS + CTX
#define K_CIN  256
#define PIXELS 704      // 16*44
#define BNPAIR 24       // B*N = 4*6
#define BEVHW  16384    // 128*128
#define NBATCH 4
#define NPOINT (BNPAIR * D_BINS * PIXELS)   // 996,864
#define PPBAT  (6 * D_BINS * PIXELS)        // 249,216 points per batch

// Coarse binning: tile = 8 rows x 16 cols of BEV cells -> 128 cells/tile,
// 128 tiles/batch, 512 buckets. ~1947 points/bucket, ~15 points/cell.
#define NTILE   128
#define NBUCKET (NBATCH * NTILE)            // 512
#define TCELLS  128
#define NCELL   (NBATCH * BEVHW)            // 65,536
#define GCELLS  16                          // cells per gather block

// Workspace layout (4B units, all offsets even -> 8B aligned):
#define XDEPTH_OFF 0
#define CTX_OFF    (XDEPTH_OFF + NPOINT)
#define COUNTS_OFF (CTX_OFF + BNPAIR * PIXELS * CTX)
#define OFFS_OFF   (COUNTS_OFF + NBUCKET)
#define FILLP_OFF  (OFFS_OFF + NBUCKET)        // padded cursors: 16 ints each
#define OFFS2_OFF  (FILLP_OFF + NBUCKET * 16)
#define CNTS2_OFF  (OFFS2_OFF + NCELL)
#define PLIST1_OFF (CNTS2_OFF + NCELL)
#define PLIST2_OFF (PLIST1_OFF + 2 * NPOINT)
// total = PLIST2_OFF + 2*NPOINT = 6,476,288 units = 25.9 MB

// ---------------------------------------------------------------------------
// Kernel 1: per-(b,n) GEMM (unchanged from R3).
// ---------------------------------------------------------------------------
__global__ __launch_bounds__(256) void gemm_kernel(
    const float* __restrict__ img,    // (BNPAIR, 256, 704)
    const float* __restrict__ w,      // (139, 256)
    const float* __restrict__ bias,   // (139)
    float* __restrict__ xdepth,
    float* __restrict__ ctx)
{
    __shared__ float As[16][64];
    __shared__ float Bs[16][128];

    const int tid = threadIdx.x;
    const int tx  = tid & 15;
    const int ty  = tid >> 4;
    const int bn  = blockIdx.z;
    const int o0  = blockIdx.y * 64;
    const int p0  = blockIdx.x * 128;

    const float* imgbn = img + (size_t)bn * K_CIN * PIXELS;

    float acc[4][8];
#pragma unroll
    for (int i = 0; i < 4; ++i)
#pragma unroll
        for (int j = 0; j < 8; ++j) acc[i][j] = 0.f;

    const int a_ol = tid >> 2;
    const int a_kc = (tid & 3) * 4;

    for (int kt = 0; kt < K_CIN; kt += 16) {
        {
            int o = o0 + a_ol;
            float4 v = make_float4(0.f, 0.f, 0.f, 0.f);
            if (o < O_TOT) v = *(const float4*)&w[(size_t)o * K_CIN + kt + a_kc];
            As[a_kc + 0][a_ol] = v.x;
            As[a_kc + 1][a_ol] = v.y;
            As[a_kc + 2][a_ol] = v.z;
            As[a_kc + 3][a_ol] = v.w;
        }
#pragma unroll
        for (int r = 0; r < 2; ++r) {
            int e   = tid + 256 * r;
            int k_l = e >> 5;
            int p4  = (e & 31) * 4;
            int pg  = p0 + p4;
            float4 v = make_float4(0.f, 0.f, 0.f, 0.f);
            if (pg < PIXELS) v = *(const float4*)&imgbn[(size_t)(kt + k_l) * PIXELS + pg];
            *(float4*)&Bs[k_l][p4] = v;
        }
        __syncthreads();

#pragma unroll
        for (int kk = 0; kk < 16; ++kk) {
            float4 a  = *(const float4*)&As[kk][ty * 4];
            float4 b0 = *(const float4*)&Bs[kk][tx * 8];
            float4 b1 = *(const float4*)&Bs[kk][tx * 8 + 4];
            const float av[4] = {a.x, a.y, a.z, a.w};
            const float bv[8] = {b0.x, b0.y, b0.z, b0.w, b1.x, b1.y, b1.z, b1.w};
#pragma unroll
            for (int i = 0; i < 4; ++i)
#pragma unroll
                for (int j = 0; j < 8; ++j)
                    acc[i][j] += av[i] * bv[j];
        }
        __syncthreads();
    }

    const bool full_p = (p0 + 127) < PIXELS;
#pragma unroll
    for (int i = 0; i < 4; ++i) {
        const int o = o0 + ty * 4 + i;
        if (o >= O_TOT) continue;
        const float bv = bias[o];
        if (o < D_BINS) {
            float* dst = xdepth + ((size_t)bn * D_BINS + o) * PIXELS + p0 + tx * 8;
#pragma unroll
            for (int j = 0; j < 8; ++j) {
                if (full_p || (p0 + tx * 8 + j < PIXELS)) dst[j] = acc[i][j] + bv;
            }
        } else {
            const int c = o - D_BINS;
            float* dst = ctx + ((size_t)bn * PIXELS + p0 + tx * 8) * CTX + c;
#pragma unroll
            for (int j = 0; j < 8; ++j) {
                if (full_p || (p0 + tx * 8 + j < PIXELS)) dst[(size_t)j * CTX] = acc[i][j] + bv;
            }
        }
    }
}

// ---------------------------------------------------------------------------
// Kernel 2: softmax over 59 depth bins, thread-per-pixel (unchanged).
// ---------------------------------------------------------------------------
__global__ __launch_bounds__(256) void softmax_kernel(float* __restrict__ xdepth)
{
    const int pix = blockIdx.x * 256 + threadIdx.x;   // < 16896 exactly
    const int bn  = pix / PIXELS;
    const int pp  = pix - bn * PIXELS;
    float* base = xdepth + ((size_t)bn * D_BINS) * PIXELS + pp;

    float v[D_BINS];
    float m = -INFINITY;
#pragma unroll
    for (int d = 0; d < D_BINS; ++d) {
        v[d] = base[(size_t)d * PIXELS];
        m = fmaxf(m, v[d]);
    }
    float s = 0.f;
#pragma unroll
    for (int d = 0; d < D_BINS; ++d) {
        v[d] = __expf(v[d] - m);
        s += v[d];
    }
    const float inv = 1.f / s;
#pragma unroll
    for (int d = 0; d < D_BINS; ++d)
        base[(size_t)d * PIXELS] = v[d] * inv;
}

// ---------------------------------------------------------------------------
// Kernel 3: histogram over 512 (b,tile) buckets (LDS, then one flush/block).
// ---------------------------------------------------------------------------
__global__ __launch_bounds__(1024) void hist_kernel(
    const int* __restrict__ geom, int* __restrict__ counts)
{
    __shared__ int h[NBUCKET];
    const int tid = threadIdx.x;
    if (tid < NBUCKET) h[tid] = 0;
    __syncthreads();

    const int base = blockIdx.x * 4096;
#pragma unroll
    for (int r = 0; r < 4; ++r) {
        const int pt = base + r * 1024 + tid;
        if (pt < NPOINT) {
            const int g0 = geom[2 * (size_t)pt];
            const int g1 = geom[2 * (size_t)pt + 1];
            const int b  = pt / PPBAT;
            atomicAdd(&h[b * NTILE + (g0 >> 3) * 8 + (g1 >> 4)], 1);
        }
    }
    __syncthreads();
    if (tid < NBUCKET && h[tid]) atomicAdd(&counts[tid], h[tid]);
}

// ---------------------------------------------------------------------------
// Kernel 4: exclusive scan over 512 bucket counts; init padded fill cursors.
// ---------------------------------------------------------------------------
__global__ __launch_bounds__(NBUCKET) void scan_kernel(
    const int* __restrict__ counts, int* __restrict__ offs, int* __restrict__ fillp)
{
    __shared__ int s[NBUCKET];
    const int tid = threadIdx.x;
    const int v   = counts[tid];
    s[tid] = v;
    __syncthreads();
#pragma unroll
    for (int off = 1; off < NBUCKET; off <<= 1) {
        int t = (tid >= off) ? s[tid - off] : 0;
        __syncthreads();
        s[tid] += t;
        __syncthreads();
    }
    const int e = s[tid] - v;
    offs[tid] = e;
    fillp[tid * 16] = e;
}

// ---------------------------------------------------------------------------
// Kernel 5 (fillA): append points to coarse buckets with CHUNK RESERVATION:
// per-block LDS histogram, ONE global atomic per (block,bucket), then in-block
// placement via LDS int cursors. Kills R4's 1947-deep global-cursor
// serialization AND R3's 59MB scattered writeback.
// entry = { depth_bits, (ctx_offset << 7) | cell_in_tile }
// ---------------------------------------------------------------------------
__global__ __launch_bounds__(1024) void fill_kernel(
    const int*   __restrict__ geom,
    const float* __restrict__ xdepth,
    int*         __restrict__ fillp,
    uint2*       __restrict__ plist1)
{
    __shared__ int h[NBUCKET];
    __shared__ int basearr[NBUCKET];
    __shared__ int cur[NBUCKET];
    const int tid = threadIdx.x;
    if (tid < NBUCKET) { h[tid] = 0; cur[tid] = 0; }
    __syncthreads();

    const int base = blockIdx.x * 4096;
    int   bk[4];
    uint2 ent[4];
    bool  valid[4];
#pragma unroll
    for (int r = 0; r < 4; ++r) {
        const int pt = base + r * 1024 + tid;
        valid[r] = (pt < NPOINT);
        if (valid[r]) {
            const int g0  = geom[2 * (size_t)pt];
            const int g1  = geom[2 * (size_t)pt + 1];
            const int bnd = pt / PIXELS;
            const int pp  = pt - bnd * PIXELS;
            const int bn  = bnd / D_BINS;
            const int b   = bn / 6;
            bk[r] = b * NTILE + (g0 >> 3) * 8 + (g1 >> 4);
            const int cell = (g0 & 7) * 16 + (g1 & 15);
            ent[r] = make_uint2(__float_as_uint(xdepth[pt]),
                                ((unsigned)((bn * PIXELS + pp) * CTX) << 7) | (unsigned)cell);
            atomicAdd(&h[bk[r]], 1);
        }
    }
    __syncthreads();
    if (tid < NBUCKET && h[tid]) basearr[tid] = atomicAdd(&fillp[tid * 16], h[tid]);
    __syncthreads();
#pragma unroll
    for (int r = 0; r < 4; ++r) {
        if (valid[r]) {
            const int pos = basearr[bk[r]] + atomicAdd(&cur[bk[r]], 1);
            plist1[pos] = ent[r];
        }
    }
}

// ---------------------------------------------------------------------------
// Kernel 6 (sortB): one block per bucket. LDS count over 128 cells (int
// atomics), LDS scan, emit plist2 ordered by cell + per-cell offs/cnts.
// ---------------------------------------------------------------------------
__global__ __launch_bounds__(512) void sort_kernel(
    const uint2* __restrict__ plist1,
    const int*   __restrict__ counts,
    const int*   __restrict__ offs,
    uint2*       __restrict__ plist2,
    int*         __restrict__ offs2,
    int*         __restrict__ cnts2)
{
    __shared__ int cellcnt[TCELLS];
    __shared__ int celloff[TCELLS];
    __shared__ int cellcur[TCELLS];
    __shared__ int s[TCELLS];
    const int tid    = threadIdx.x;
    const int bucket = blockIdx.x;
    const int start  = offs[bucket];
    const int cnt    = counts[bucket];

    if (tid < TCELLS) { cellcnt[tid] = 0; cellcur[tid] = 0; }
    __syncthreads();

    for (int i = tid; i < cnt; i += 512)
        atomicAdd(&cellcnt[plist1[start + i].y & 127u], 1);
    __syncthreads();

    if (tid < TCELLS) s[tid] = cellcnt[tid];
    __syncthreads();
#pragma unroll
    for (int off = 1; off < TCELLS; off <<= 1) {
        int t = (tid >= off && tid < TCELLS) ? s[tid - off] : 0;
        __syncthreads();
        if (tid < TCELLS) s[tid] += t;
        __syncthreads();
    }
    if (tid < TCELLS) celloff[tid] = s[tid] - cellcnt[tid];
    __syncthreads();

    for (int i = tid; i < cnt; i += 512) {
        const uint2 e = plist1[start + i];
        const int c   = (int)(e.y & 127u);
        const int pos = start + celloff[c] + atomicAdd(&cellcur[c], 1);
        plist2[pos] = make_uint2(e.x, e.y >> 7);
    }

    if (tid < TCELLS) {
        const int b  = bucket >> 7;
        const int tl = bucket & 127;
        const int tr = tl >> 3;
        const int tc = tl & 7;
        const int g0 = tr * 8 + (tid >> 4);
        const int g1 = tc * 16 + (tid & 15);
        const int idx = b * BEVHW + g0 * 128 + g1;
        offs2[idx] = start + celloff[tid];
        cnts2[idx] = cellcnt[tid];
    }
}

// ---------------------------------------------------------------------------
// Kernel 7: gather (R3 structure — proven fast). 1024-thr block = 16 waves =
// 16 consecutive (b,cell)s (contiguous in plist2). Register accumulate,
// LDS-staged fully-coalesced writes to (B,C,H,W).
// ---------------------------------------------------------------------------
__global__ __launch_bounds__(1024) void gather_kernel(
    const uint2* __restrict__ plist2,
    const int*   __restrict__ offs2,
    const int*   __restrict__ cnts2,
    const float* __restrict__ ctx,
    float*       __restrict__ out)
{
    __shared__ float sacc[CTX][GCELLS + 1];

    const int wv   = threadIdx.x >> 6;
    const int lane = threadIdx.x & 63;
    const int wid  = blockIdx.x * GCELLS + wv;
    const int start = offs2[wid];
    const int cnt   = cnts2[wid];

    float a0 = 0.f, a1 = 0.f;
    int i = 0;
    for (; i + 1 < cnt; i += 2) {
        const uint2 p0 = plist2[start + i];
        const uint2 p1 = plist2[start + i + 1];
        const float d0 = __uint_as_float(p0.x);
        const float d1 = __uint_as_float(p1.x);
        const float* c0 = ctx + p0.y;
        const float* c1 = ctx + p1.y;
        const float v0 = c0[lane];
        const float v1 = c1[lane];
        a0 += d0 * v0;
        a0 += d1 * v1;
        if (lane < 16) {
            a1 += d0 * c0[64 + lane];
            a1 += d1 * c1[64 + lane];
        }
    }
    if (i < cnt) {
        const uint2 pe = plist2[start + i];
        const float dep = __uint_as_float(pe.x);
        const float* cb = ctx + pe.y;
        a0 += dep * cb[lane];
        if (lane < 16) a1 += dep * cb[64 + lane];
    }

    sacc[lane][wv] = a0;
    if (lane < 16) sacc[64 + lane][wv] = a1;
    __syncthreads();

    const int c0 = threadIdx.x >> 4;
    const int cl = threadIdx.x & 15;
    const int widbase  = blockIdx.x * GCELLS;
    const int b        = widbase >> 14;
    const int cellbase = widbase & (BEVHW - 1);
#pragma unroll
    for (int cc = c0; cc < CTX; cc += 64)
        out[((size_t)(b * CTX + cc)) * BEVHW + cellbase + cl] = sacc[cc][cl];
}

extern "C" void kernel_launch(void* const* d_in, const int* in_sizes, int n_in,
                              void* d_out, int out_size, void* d_ws, size_t ws_size,
                              hipStream_t stream)
{
    const float* img  = (const float*)d_in[0];
    const float* w    = (const float*)d_in[4];
    const float* bias = (const float*)d_in[5];
    const int*   geom = (const int*)d_in[6];
    float*       out  = (float*)d_out;

    float* ws     = (float*)d_ws;
    float* xdepth = ws + XDEPTH_OFF;
    float* ctx    = ws + CTX_OFF;
    int*   counts = (int*)(ws + COUNTS_OFF);
    int*   offs   = (int*)(ws + OFFS_OFF);
    int*   fillp  = (int*)(ws + FILLP_OFF);
    int*   offs2  = (int*)(ws + OFFS2_OFF);
    int*   cnts2  = (int*)(ws + CNTS2_OFF);
    uint2* plist1 = (uint2*)(ws + PLIST1_OFF);
    uint2* plist2 = (uint2*)(ws + PLIST2_OFF);

    // bucket counters must start at zero (ws is poisoned 0xAA each call)
    hipMemsetAsync(counts, 0, NBUCKET * sizeof(int), stream);

    // 1. GEMM + bias -> depth logits / transposed context
    {
        dim3 grid(6, 3, BNPAIR);
        gemm_kernel<<<grid, 256, 0, stream>>>(img, w, bias, xdepth, ctx);
    }
    // 2. softmax over depth bins
    softmax_kernel<<<(BNPAIR * PIXELS) / 256, 256, 0, stream>>>(xdepth);

    // 3. two-pass counting sort: coarse buckets, then cell order within bucket
    hist_kernel<<<(NPOINT + 4095) / 4096, 1024, 0, stream>>>(geom, counts);
    scan_kernel<<<1, NBUCKET, 0, stream>>>(counts, offs, fillp);
    fill_kernel<<<(NPOINT + 4095) / 4096, 1024, 0, stream>>>(geom, xdepth, fillp, plist1);
    sort_kernel<<<NBUCKET, 512, 0, stream>>>(plist1, counts, offs, plist2, offs2, cnts2);

    // 4. gather per (b,cell), LDS-staged coalesced writes to (B,C,H,W)
    gather_kernel<<<NCELL / GCELLS, 1024, 0, stream>>>(plist2, offs2, cnts2, ctx, out);
}

// Round 6
// 187.586 us; speedup vs baseline: 3.5709x; 1.1023x over previous
//
#include <hip/hip_runtime.h>
#include <hip/hip_bf16.h>
#include <math.h>

// Problem constants (from reference)
#define D_BINS 59
#define CTX    80
#define O_TOT  139      // D_BINS + CTX
#define K_CIN  256
#define PIXELS 704      // 16*44
#define BNPAIR 24       // B*N = 4*6
#define BEVHW  16384    // 128*128
#define NBATCH 4
#define NPOINT (BNPAIR * D_BINS * PIXELS)   // 996,864
#define NPIX   (BNPAIR * PIXELS)            // 16,896

// Coarse binning: tile = 8 rows x 16 cols of BEV cells -> 128 cells/tile,
// 128 tiles/batch, 512 buckets. ~1947 points/bucket, ~15 points/cell.
#define NTILE   128
#define NBUCKET (NBATCH * NTILE)            // 512
#define TCELLS  128

// Fill blocks: 256 pixels each -> 66 blocks, 15,104 entries per block region.
#define NBLK    (NPIX / 256)                // 66
#define EPB     (256 * D_BINS)              // 15,104 entries per block

// Gather LDS list capacity: bucket mean 1947, sd ~44 -> 2816 is ~20 sigma.
// (Correct slow-path fallback exists for cnt > CAP.)
#define CAP     2816

// Workspace layout (4B units):
#define XDEPTH_OFF 0
#define CTX_OFF    (XDEPTH_OFF + NPOINT)
#define CNTMAT_OFF (CTX_OFF + BNPAIR * PIXELS * CTX)
#define OFSMAT_OFF (CNTMAT_OFF + NBLK * NBUCKET)
#define PLIST_OFF  (OFSMAT_OFF + NBLK * NBUCKET)
// total = PLIST_OFF + 2*NPOINT ~ 17.6 MB

// ---------------------------------------------------------------------------
// Kernel 1: per-(b,n) GEMM (proven; unchanged).
// ---------------------------------------------------------------------------
__global__ __launch_bounds__(256) void gemm_kernel(
    const float* __restrict__ img,    // (BNPAIR, 256, 704)
    const float* __restrict__ w,      // (139, 256)
    const float* __restrict__ bias,   // (139)
    float* __restrict__ xdepth,       // (bn, 59, 704) depth LOGITS
    float* __restrict__ ctx)          // (bn, 704, 80) context (bias applied)
{
    __shared__ float As[16][64];
    __shared__ float Bs[16][128];

    const int tid = threadIdx.x;
    const int tx  = tid & 15;
    const int ty  = tid >> 4;
    const int bn  = blockIdx.z;
    const int o0  = blockIdx.y * 64;
    const int p0  = blockIdx.x * 128;

    const float* imgbn = img + (size_t)bn * K_CIN * PIXELS;

    float acc[4][8];
#pragma unroll
    for (int i = 0; i < 4; ++i)
#pragma unroll
        for (int j = 0; j < 8; ++j) acc[i][j] = 0.f;

    const int a_ol = tid >> 2;
    const int a_kc = (tid & 3) * 4;

    for (int kt = 0; kt < K_CIN; kt += 16) {
        {
            int o = o0 + a_ol;
            float4 v = make_float4(0.f, 0.f, 0.f, 0.f);
            if (o < O_TOT) v = *(const float4*)&w[(size_t)o * K_CIN + kt + a_kc];
            As[a_kc + 0][a_ol] = v.x;
            As[a_kc + 1][a_ol] = v.y;
            As[a_kc + 2][a_ol] = v.z;
            As[a_kc + 3][a_ol] = v.w;
        }
#pragma unroll
        for (int r = 0; r < 2; ++r) {
            int e   = tid + 256 * r;
            int k_l = e >> 5;
            int p4  = (e & 31) * 4;
            int pg  = p0 + p4;
            float4 v = make_float4(0.f, 0.f, 0.f, 0.f);
            if (pg < PIXELS) v = *(const float4*)&imgbn[(size_t)(kt + k_l) * PIXELS + pg];
            *(float4*)&Bs[k_l][p4] = v;
        }
        __syncthreads();

#pragma unroll
        for (int kk = 0; kk < 16; ++kk) {
            float4 a  = *(const float4*)&As[kk][ty * 4];
            float4 b0 = *(const float4*)&Bs[kk][tx * 8];
            float4 b1 = *(const float4*)&Bs[kk][tx * 8 + 4];
            const float av[4] = {a.x, a.y, a.z, a.w};
            const float bv[8] = {b0.x, b0.y, b0.z, b0.w, b1.x, b1.y, b1.z, b1.w};
#pragma unroll
            for (int i = 0; i < 4; ++i)
#pragma unroll
                for (int j = 0; j < 8; ++j)
                    acc[i][j] += av[i] * bv[j];
        }
        __syncthreads();
    }

    const bool full_p = (p0 + 127) < PIXELS;
#pragma unroll
    for (int i = 0; i < 4; ++i) {
        const int o = o0 + ty * 4 + i;
        if (o >= O_TOT) continue;
        const float bv = bias[o];
        if (o < D_BINS) {
            float* dst = xdepth + ((size_t)bn * D_BINS + o) * PIXELS + p0 + tx * 8;
#pragma unroll
            for (int j = 0; j < 8; ++j) {
                if (full_p || (p0 + tx * 8 + j < PIXELS)) dst[j] = acc[i][j] + bv;
            }
        } else {
            const int c = o - D_BINS;
            float* dst = ctx + ((size_t)bn * PIXELS + p0 + tx * 8) * CTX + c;
#pragma unroll
            for (int j = 0; j < 8; ++j) {
                if (full_p || (p0 + tx * 8 + j < PIXELS)) dst[(size_t)j * CTX] = acc[i][j] + bv;
            }
        }
    }
}

// ---------------------------------------------------------------------------
// Kernel 2 (fill): softmax + binning, fused, ZERO global atomics.
// Block = 256 pixels. Each thread: softmax over its 59 logits (registers),
// geom -> (bucket,cell) u16 cached in LDS, block-local LDS hist + scan, then
// entries placed bucket-sorted into the block's PRIVATE plist region.
// Emits per-(block,bucket) count & offset rows for the gather.
// ---------------------------------------------------------------------------
__global__ __launch_bounds__(256) void fill_kernel(
    const float* __restrict__ xdepth,   // logits (bn, 59, 704)
    const int*   __restrict__ geom,     // (pt, 2)
    uint2*       __restrict__ plist,    // [NBLK][EPB]
    int*         __restrict__ cntmat,   // [NBLK][NBUCKET]
    int*         __restrict__ ofsmat)   // [NBLK][NBUCKET]
{
    __shared__ unsigned short cache[D_BINS][256];
    __shared__ int lh[NBUCKET];
    __shared__ int lofs[NBUCKET];
    __shared__ int lcur[NBUCKET];
    __shared__ int s[256];

    const int tid = threadIdx.x;
    const int pix = blockIdx.x * 256 + tid;     // < NPIX exactly
    const int bn  = pix / PIXELS;
    const int pp  = pix - bn * PIXELS;
    const int b   = bn / 6;

    if (tid < NBUCKET) { lh[tid] = 0; lh[tid + 256] = 0; }
    __syncthreads();

    // softmax over depth bins (registers)
    const float* base = xdepth + (size_t)bn * D_BINS * PIXELS + pp;
    float v[D_BINS];
    float m = -INFINITY;
#pragma unroll
    for (int d = 0; d < D_BINS; ++d) {
        v[d] = base[(size_t)d * PIXELS];
        m = fmaxf(m, v[d]);
    }
    float sum = 0.f;
#pragma unroll
    for (int d = 0; d < D_BINS; ++d) {
        v[d] = __expf(v[d] - m);
        sum += v[d];
    }
    const float inv = 1.f / sum;
#pragma unroll
    for (int d = 0; d < D_BINS; ++d) v[d] *= inv;

    // pass 1: geom -> u16 (bucket<<7 | cell) in LDS, LDS histogram
    const int2* g2 = (const int2*)geom;
#pragma unroll
    for (int d = 0; d < D_BINS; ++d) {
        const int2 g = g2[((size_t)(bn * D_BINS + d)) * PIXELS + pp];
        const int bucket = b * NTILE + (g.x >> 3) * 8 + (g.y >> 4);
        const int cell   = (g.x & 7) * 16 + (g.y & 15);
        cache[d][tid] = (unsigned short)((bucket << 7) | cell);
        atomicAdd(&lh[bucket], 1);
    }
    __syncthreads();

    // exclusive scan over 512 buckets with 256 threads (pairwise)
    const int v0 = lh[2 * tid];
    const int v1 = lh[2 * tid + 1];
    const int p  = v0 + v1;
    s[tid] = p;
    __syncthreads();
#pragma unroll
    for (int off = 1; off < 256; off <<= 1) {
        int t = (tid >= off) ? s[tid - off] : 0;
        __syncthreads();
        s[tid] += t;
        __syncthreads();
    }
    const int excl = s[tid] - p;
    lofs[2 * tid]     = excl;
    lofs[2 * tid + 1] = excl + v0;
    lcur[2 * tid]     = 0;
    lcur[2 * tid + 1] = 0;
    // emit rows (deterministic layout: no global atomics anywhere)
    cntmat[(size_t)blockIdx.x * NBUCKET + 2 * tid]     = v0;
    cntmat[(size_t)blockIdx.x * NBUCKET + 2 * tid + 1] = v1;
    ofsmat[(size_t)blockIdx.x * NBUCKET + 2 * tid]     = excl;
    ofsmat[(size_t)blockIdx.x * NBUCKET + 2 * tid + 1] = excl + v0;
    __syncthreads();

    // pass 2: place entries bucket-sorted into the block's private region
    uint2* dst = plist + (size_t)blockIdx.x * EPB;
    const unsigned ctxoff = (unsigned)((bn * PIXELS + pp) * CTX);
#pragma unroll
    for (int d = 0; d < D_BINS; ++d) {
        const unsigned u = cache[d][tid];
        const int bucket = (int)(u >> 7);
        const int pos = lofs[bucket] + atomicAdd(&lcur[bucket], 1);
        dst[pos] = make_uint2(__float_as_uint(v[d]), (ctxoff << 7) | (u & 127u));
    }
}

// ---------------------------------------------------------------------------
// Kernel 3 (gather): one block per bucket (1024 thr = 16 waves).
// Walk the 66 per-block segments into LDS bufA, cell-sort (int LDS atomics)
// into bufB, then wave wv accumulates cells {c : c%16==wv} in REGISTERS
// (4-pt ILP; points from LDS, ctx coalesced from L2), stage into sacc,
// epilogue writes full 64B lines to (B,C,H,W). bufA overlays sacc.
// ---------------------------------------------------------------------------
__global__ __launch_bounds__(1024) void gather_kernel(
    const uint2* __restrict__ plist,
    const int*   __restrict__ cntmat,
    const int*   __restrict__ ofsmat,
    const float* __restrict__ ctx,
    float*       __restrict__ out)
{
    __shared__ float sacc[CTX][TCELLS + 1];   // 80 x 129 x 4B = 41.3 KB
    __shared__ uint2 bufB[CAP];               // 22.5 KB
    __shared__ int segcnt[NBLK], segofs[NBLK];
    __shared__ int cellcnt[TCELLS], celloff[TCELLS], cellcur[TCELLS], sc[TCELLS];
    __shared__ int sh_total;
    uint2* bufA = (uint2*)sacc;               // overlay: bufA dead once sacc live

    const int tid    = threadIdx.x;
    const int wv     = tid >> 6;
    const int lane   = tid & 63;
    const int bucket = blockIdx.x;

    if (tid < NBLK) segcnt[tid] = cntmat[(size_t)tid * NBUCKET + bucket];
    __syncthreads();
    if (tid == 0) {
        int acc = 0;
        for (int i = 0; i < NBLK; ++i) { segofs[i] = acc; acc += segcnt[i]; }
        sh_total = acc;
    }
    __syncthreads();
    const int total = sh_total;

    // load segments into bufA (wave w handles blocks w, w+16, ...)
    for (int blk = wv; blk < NBLK; blk += 16) {
        const int n = segcnt[blk];
        if (!n) continue;
        const int dstb = segofs[blk];
        const uint2* sp = plist + (size_t)blk * EPB + ofsmat[(size_t)blk * NBUCKET + bucket];
        for (int i = lane; i < n; i += 64) {
            const int d = dstb + i;
            if (d < CAP) bufA[d] = sp[i];
        }
    }
    const int ncap = (total < CAP) ? total : CAP;
    __syncthreads();

    // cell histogram + scan (128 cells)
    if (tid < TCELLS) cellcnt[tid] = 0;
    __syncthreads();
    for (int i = tid; i < ncap; i += 1024)
        atomicAdd(&cellcnt[bufA[i].y & 127u], 1);
    __syncthreads();
    if (tid < TCELLS) sc[tid] = cellcnt[tid];
    __syncthreads();
#pragma unroll
    for (int off = 1; off < TCELLS; off <<= 1) {
        int t = (tid < TCELLS && tid >= off) ? sc[tid - off] : 0;
        __syncthreads();
        if (tid < TCELLS) sc[tid] += t;
        __syncthreads();
    }
    if (tid < TCELLS) { celloff[tid] = sc[tid] - cellcnt[tid]; cellcur[tid] = 0; }
    __syncthreads();

    // reorder bufA -> bufB (cell-sorted)
    for (int i = tid; i < ncap; i += 1024) {
        const uint2 e = bufA[i];
        const int c = (int)(e.y & 127u);
        bufB[celloff[c] + atomicAdd(&cellcur[c], 1)] = e;
    }
    __syncthreads();   // bufA dead; sacc live from here

    // accumulate: wave wv owns cells c = wv, wv+16, ..., wv+112
    for (int c = wv; c < TCELLS; c += 16) {
        const int s0 = celloff[c];
        const int n  = cellcnt[c];
        float a0 = 0.f, a1 = 0.f;
        int i = 0;
        for (; i + 3 < n; i += 4) {
            const uint2 e0 = bufB[s0 + i];
            const uint2 e1 = bufB[s0 + i + 1];
            const uint2 e2 = bufB[s0 + i + 2];
            const uint2 e3 = bufB[s0 + i + 3];
            const float* p0 = ctx + (e0.y >> 7);
            const float* p1 = ctx + (e1.y >> 7);
            const float* p2 = ctx + (e2.y >> 7);
            const float* p3 = ctx + (e3.y >> 7);
            const float d0 = __uint_as_float(e0.x);
            const float d1 = __uint_as_float(e1.x);
            const float d2 = __uint_as_float(e2.x);
            const float d3 = __uint_as_float(e3.x);
            a0 += d0 * p0[lane] + d1 * p1[lane] + d2 * p2[lane] + d3 * p3[lane];
            if (lane < 16)
                a1 += d0 * p0[64 + lane] + d1 * p1[64 + lane]
                    + d2 * p2[64 + lane] + d3 * p3[64 + lane];
        }
        for (; i < n; ++i) {
            const uint2 e = bufB[s0 + i];
            const float* pb = ctx + (e.y >> 7);
            const float dep = __uint_as_float(e.x);
            a0 += dep * pb[lane];
            if (lane < 16) a1 += dep * pb[64 + lane];
        }
        sacc[lane][c] = a0;
        if (lane < 16) sacc[64 + lane][c] = a1;
    }

    // slow path for bucket overflow (never triggers at ~20 sigma; correctness)
    if (total > CAP) {
        for (int blk = 0; blk < NBLK; ++blk) {
            const int dstb = segofs[blk];
            const int n    = segcnt[blk];
            if (dstb + n <= CAP) continue;
            const uint2* sp = plist + (size_t)blk * EPB + ofsmat[(size_t)blk * NBUCKET + bucket];
            const int i0 = (CAP > dstb) ? (CAP - dstb) : 0;
            for (int i = i0; i < n; ++i) {
                const uint2 e = sp[i];          // broadcast
                const int c = (int)(e.y & 127u);
                if ((c & 15) == wv) {
                    const float* pb = ctx + (e.y >> 7);
                    const float dep = __uint_as_float(e.x);
                    sacc[lane][c] += dep * pb[lane];
                    if (lane < 16) sacc[64 + lane][c] += dep * pb[64 + lane];
                }
            }
        }
    }
    __syncthreads();

    // epilogue: bucket -> (b, tr, tc); 16-consecutive-thread 64B line writes
    const int b  = bucket >> 7;
    const int tl = bucket & 127;
    const int tr = tl >> 3;
    const int tc = tl & 7;
    const int c0  = tid >> 4;       // 0..63
    const int col = tid & 15;
#pragma unroll
    for (int cc = c0; cc < CTX; cc += 64) {
#pragma unroll
        for (int r = 0; r < 8; ++r) {
            out[((size_t)(b * CTX + cc)) * BEVHW + (tr * 8 + r) * 128 + tc * 16 + col]
                = sacc[cc][r * 16 + col];
        }
    }
}

extern "C" void kernel_launch(void* const* d_in, const int* in_sizes, int n_in,
                              void* d_out, int out_size, void* d_ws, size_t ws_size,
                              hipStream_t stream)
{
    const float* img  = (const float*)d_in[0];
    const float* w    = (const float*)d_in[4];
    const float* bias = (const float*)d_in[5];
    const int*   geom = (const int*)d_in[6];
    float*       out  = (float*)d_out;

    float* ws     = (float*)d_ws;
    float* xdepth = ws + XDEPTH_OFF;
    float* ctx    = ws + CTX_OFF;
    int*   cntmat = (int*)(ws + CNTMAT_OFF);
    int*   ofsmat = (int*)(ws + OFSMAT_OFF);
    uint2* plist  = (uint2*)(ws + PLIST_OFF);

    // 1. GEMM + bias -> depth logits (bn,d,pix) / transposed context (bn,pix,c)
    {
        dim3 grid(6, 3, BNPAIR);
        gemm_kernel<<<grid, 256, 0, stream>>>(img, w, bias, xdepth, ctx);
    }
    // 2. fused softmax + deterministic block-local counting sort (no atomics)
    fill_kernel<<<NBLK, 256, 0, stream>>>(xdepth, geom, plist, cntmat, ofsmat);

    // 3. fused cell-sort + gather per bucket, coalesced (B,C,H,W) writes
    gather_kernel<<<NBUCKET, 1024, 0, stream>>>(plist, cntmat, ofsmat, ctx, out);
}

// Round 7
// 172.646 us; speedup vs baseline: 3.8799x; 1.0865x over previous
//
#include <hip/hip_runtime.h>
#include <hip/hip_bf16.h>
#include <math.h>

// Problem constants (from reference)
#define D_BINS 59
#define CTX    80
#define O_TOT  139      // D_BINS + CTX
#define K_CIN  256
#define PIXELS 704      // 16*44
#define BNPAIR 24       // B*N = 4*6
#define BEVHW  16384    // 128*128
#define NBATCH 4
#define NPOINT (BNPAIR * D_BINS * PIXELS)   // 996,864
#define NPIX   (BNPAIR * PIXELS)            // 16,896

// Coarse binning: tile = 8 rows x 16 cols of BEV cells -> 128 cells/tile,
// 128 tiles/batch, 512 buckets. ~1947 points/bucket, ~15 points/cell.
#define NTILE   128
#define NBUCKET (NBATCH * NTILE)            // 512
#define TCELLS  128

// Fill blocks: 256 pixels each -> 66 blocks, 15,104 entries per block region.
#define NBLK    (NPIX / 256)                // 66
#define EPB     (256 * D_BINS)              // 15,104 entries per block

// Gather LDS list capacity (bucket mean 1947, sd ~44; slow-path covers >CAP).
#define CAP     2816
#define CAPP    (CAP + TCELLS * 7)          // + max pad-to-8 slack

// Workspace layout (4B units):
#define XDEPTH_OFF 0
#define CTX_OFF    (XDEPTH_OFF + NPOINT)
#define CNTMAT_OFF (CTX_OFF + BNPAIR * PIXELS * CTX)
#define OFSMAT_OFF (CNTMAT_OFF + NBLK * NBUCKET)
#define PLIST_OFF  (OFSMAT_OFF + NBLK * NBUCKET)

// ---------------------------------------------------------------------------
// Kernel 1: per-(b,n) GEMM. 64x64 tile (704 = 11*64: no pixel tail),
// 4x4 micro-tile, conflict-free inner-loop LDS reads:
//   B: Bs[kk][tx*4]  -> 16 addrs over all 32 banks, 2-way (free per m136)
//   A: As[kk][ty*4]  -> 4 addrs, 16-lane broadcast (free)
// Grid 11*3*24 = 792 blocks (vs 432) for ~2x occupancy.
// ---------------------------------------------------------------------------
__global__ __launch_bounds__(256) void gemm_kernel(
    const float* __restrict__ img,    // (BNPAIR, 256, 704)
    const float* __restrict__ w,      // (139, 256)
    const float* __restrict__ bias,   // (139)
    float* __restrict__ xdepth,       // (bn, 59, 704) depth LOGITS
    float* __restrict__ ctx)          // (bn, 704, 80) context (bias applied)
{
    __shared__ float As[16][64];    // [k][o_local]
    __shared__ float Bs[16][64];    // [k][p_local]

    const int tid = threadIdx.x;
    const int tx  = tid & 15;      // pixel group: owns pixels tx*4..tx*4+3
    const int ty  = tid >> 4;      // output group: owns o ty*4..ty*4+3
    const int bn  = blockIdx.z;
    const int o0  = blockIdx.y * 64;
    const int p0  = blockIdx.x * 64;

    const float* imgbn = img + (size_t)bn * K_CIN * PIXELS;

    float acc[4][4];
#pragma unroll
    for (int i = 0; i < 4; ++i)
#pragma unroll
        for (int j = 0; j < 4; ++j) acc[i][j] = 0.f;

    const int a_ol = tid >> 2;          // 0..63
    const int a_kc = (tid & 3) * 4;     // 0,4,8,12
    const int b_kl = tid >> 4;          // 0..15
    const int b_p4 = (tid & 15) * 4;    // 0..60

    for (int kt = 0; kt < K_CIN; kt += 16) {
        // A tile: 64 o x 16 k, one float4 per thread
        {
            const int o = o0 + a_ol;
            float4 v = make_float4(0.f, 0.f, 0.f, 0.f);
            if (o < O_TOT) v = *(const float4*)&w[(size_t)o * K_CIN + kt + a_kc];
            As[a_kc + 0][a_ol] = v.x;
            As[a_kc + 1][a_ol] = v.y;
            As[a_kc + 2][a_ol] = v.z;
            As[a_kc + 3][a_ol] = v.w;
        }
        // B tile: 16 k x 64 p, one float4 per thread, coalesced 256B/row
        *(float4*)&Bs[b_kl][b_p4] =
            *(const float4*)&imgbn[(size_t)(kt + b_kl) * PIXELS + p0 + b_p4];
        __syncthreads();

#pragma unroll
        for (int kk = 0; kk < 16; ++kk) {
            const float4 a = *(const float4*)&As[kk][ty * 4];
            const float4 b = *(const float4*)&Bs[kk][tx * 4];
            const float av[4] = {a.x, a.y, a.z, a.w};
            const float bv[4] = {b.x, b.y, b.z, b.w};
#pragma unroll
            for (int i = 0; i < 4; ++i)
#pragma unroll
                for (int j = 0; j < 4; ++j)
                    acc[i][j] += av[i] * bv[j];
        }
        __syncthreads();
    }

#pragma unroll
    for (int i = 0; i < 4; ++i) {
        const int o = o0 + ty * 4 + i;
        if (o >= O_TOT) continue;
        const float bv = bias[o];
        if (o < D_BINS) {
            float4 r = make_float4(acc[i][0] + bv, acc[i][1] + bv,
                                   acc[i][2] + bv, acc[i][3] + bv);
            *(float4*)&xdepth[((size_t)bn * D_BINS + o) * PIXELS + p0 + tx * 4] = r;
        } else {
            const int c = o - D_BINS;
            float* dst = ctx + ((size_t)bn * PIXELS + p0 + tx * 4) * CTX + c;
#pragma unroll
            for (int j = 0; j < 4; ++j) dst[(size_t)j * CTX] = acc[i][j] + bv;
        }
    }
}

// ---------------------------------------------------------------------------
// Kernel 2 (fill): softmax + binning, fused, ZERO global atomics (unchanged).
// ---------------------------------------------------------------------------
__global__ __launch_bounds__(256) void fill_kernel(
    const float* __restrict__ xdepth,   // logits (bn, 59, 704)
    const int*   __restrict__ geom,     // (pt, 2)
    uint2*       __restrict__ plist,    // [NBLK][EPB]
    int*         __restrict__ cntmat,   // [NBLK][NBUCKET]
    int*         __restrict__ ofsmat)   // [NBLK][NBUCKET]
{
    __shared__ unsigned short cache[D_BINS][256];
    __shared__ int lh[NBUCKET];
    __shared__ int lofs[NBUCKET];
    __shared__ int lcur[NBUCKET];
    __shared__ int s[256];

    const int tid = threadIdx.x;
    const int pix = blockIdx.x * 256 + tid;     // < NPIX exactly
    const int bn  = pix / PIXELS;
    const int pp  = pix - bn * PIXELS;
    const int b   = bn / 6;

    if (tid < NBUCKET) { lh[tid] = 0; lh[tid + 256] = 0; }
    __syncthreads();

    const float* base = xdepth + (size_t)bn * D_BINS * PIXELS + pp;
    float v[D_BINS];
    float m = -INFINITY;
#pragma unroll
    for (int d = 0; d < D_BINS; ++d) {
        v[d] = base[(size_t)d * PIXELS];
        m = fmaxf(m, v[d]);
    }
    float sum = 0.f;
#pragma unroll
    for (int d = 0; d < D_BINS; ++d) {
        v[d] = __expf(v[d] - m);
        sum += v[d];
    }
    const float inv = 1.f / sum;
#pragma unroll
    for (int d = 0; d < D_BINS; ++d) v[d] *= inv;

    const int2* g2 = (const int2*)geom;
#pragma unroll
    for (int d = 0; d < D_BINS; ++d) {
        const int2 g = g2[((size_t)(bn * D_BINS + d)) * PIXELS + pp];
        const int bucket = b * NTILE + (g.x >> 3) * 8 + (g.y >> 4);
        const int cell   = (g.x & 7) * 16 + (g.y & 15);
        cache[d][tid] = (unsigned short)((bucket << 7) | cell);
        atomicAdd(&lh[bucket], 1);
    }
    __syncthreads();

    const int v0 = lh[2 * tid];
    const int v1 = lh[2 * tid + 1];
    const int p  = v0 + v1;
    s[tid] = p;
    __syncthreads();
#pragma unroll
    for (int off = 1; off < 256; off <<= 1) {
        int t = (tid >= off) ? s[tid - off] : 0;
        __syncthreads();
        s[tid] += t;
        __syncthreads();
    }
    const int excl = s[tid] - p;
    lofs[2 * tid]     = excl;
    lofs[2 * tid + 1] = excl + v0;
    lcur[2 * tid]     = 0;
    lcur[2 * tid + 1] = 0;
    cntmat[(size_t)blockIdx.x * NBUCKET + 2 * tid]     = v0;
    cntmat[(size_t)blockIdx.x * NBUCKET + 2 * tid + 1] = v1;
    ofsmat[(size_t)blockIdx.x * NBUCKET + 2 * tid]     = excl;
    ofsmat[(size_t)blockIdx.x * NBUCKET + 2 * tid + 1] = excl + v0;
    __syncthreads();

    uint2* dst = plist + (size_t)blockIdx.x * EPB;
    const unsigned ctxoff = (unsigned)((bn * PIXELS + pp) * CTX);
#pragma unroll
    for (int d = 0; d < D_BINS; ++d) {
        const unsigned u = cache[d][tid];
        const int bucket = (int)(u >> 7);
        const int pos = lofs[bucket] + atomicAdd(&lcur[bucket], 1);
        dst[pos] = make_uint2(__float_as_uint(v[d]), (ctxoff << 7) | (u & 127u));
    }
}

// ---------------------------------------------------------------------------
// Kernel 3 (gather): one block per bucket (1024 thr = 16 waves).
// Segments -> LDS bufA -> cell-sort into bufB with per-cell PAD-TO-8
// (pad entries depth=0: contribute nothing) so the accumulate loop is a
// clean 8-point unroll -> 8 independent L2 load chains in flight.
// ---------------------------------------------------------------------------
__global__ __launch_bounds__(1024) void gather_kernel(
    const uint2* __restrict__ plist,
    const int*   __restrict__ cntmat,
    const int*   __restrict__ ofsmat,
    const float* __restrict__ ctx,
    float*       __restrict__ out)
{
    __shared__ float sacc[CTX][TCELLS + 1];   // 41.3 KB
    __shared__ uint2 bufB[CAPP];              // 29 KB
    __shared__ int segcnt[NBLK], segofs[NBLK];
    __shared__ int cellcnt[TCELLS], celloff[TCELLS], cellcur[TCELLS], sc[TCELLS];
    __shared__ int sh_total;
    uint2* bufA = (uint2*)sacc;               // overlay: bufA dead once sacc live

    const int tid    = threadIdx.x;
    const int wv     = tid >> 6;
    const int lane   = tid & 63;
    const int bucket = blockIdx.x;

    if (tid < NBLK) segcnt[tid] = cntmat[(size_t)tid * NBUCKET + bucket];
    __syncthreads();
    if (tid == 0) {
        int acc = 0;
        for (int i = 0; i < NBLK; ++i) { segofs[i] = acc; acc += segcnt[i]; }
        sh_total = acc;
    }
    __syncthreads();
    const int total = sh_total;

    for (int blk = wv; blk < NBLK; blk += 16) {
        const int n = segcnt[blk];
        if (!n) continue;
        const int dstb = segofs[blk];
        const uint2* sp = plist + (size_t)blk * EPB + ofsmat[(size_t)blk * NBUCKET + bucket];
        for (int i = lane; i < n; i += 64) {
            const int d = dstb + i;
            if (d < CAP) bufA[d] = sp[i];
        }
    }
    const int ncap = (total < CAP) ? total : CAP;
    __syncthreads();

    // cell histogram
    if (tid < TCELLS) cellcnt[tid] = 0;
    __syncthreads();
    for (int i = tid; i < ncap; i += 1024)
        atomicAdd(&cellcnt[bufA[i].y & 127u], 1);
    __syncthreads();
    // scan over PADDED counts (round up to 8)
    if (tid < TCELLS) sc[tid] = (cellcnt[tid] + 7) & ~7;
    __syncthreads();
#pragma unroll
    for (int off = 1; off < TCELLS; off <<= 1) {
        int t = (tid < TCELLS && tid >= off) ? sc[tid - off] : 0;
        __syncthreads();
        if (tid < TCELLS) sc[tid] += t;
        __syncthreads();
    }
    if (tid < TCELLS) {
        celloff[tid] = sc[tid] - ((cellcnt[tid] + 7) & ~7);
        cellcur[tid] = 0;
    }
    __syncthreads();
    const int padtotal = sc[TCELLS - 1];
    // zero pad region (pads: depth=0 -> contribute 0; ctxoff=0 harmless)
    for (int i = tid; i < padtotal; i += 1024) bufB[i] = make_uint2(0u, 0u);
    __syncthreads();
    // reorder bufA -> bufB (cell-sorted, padded)
    for (int i = tid; i < ncap; i += 1024) {
        const uint2 e = bufA[i];
        const int c = (int)(e.y & 127u);
        bufB[celloff[c] + atomicAdd(&cellcur[c], 1)] = e;
    }
    __syncthreads();   // bufA dead; sacc live from here

    // accumulate: wave wv owns cells c = wv, wv+16, ... ; 8-pt unrolled
    for (int c = wv; c < TCELLS; c += 16) {
        const int s0 = celloff[c];
        const int pc = (cellcnt[c] + 7) & ~7;
        float a0 = 0.f, a1 = 0.f;
        for (int i = 0; i < pc; i += 8) {
            uint2 e[8];
#pragma unroll
            for (int r = 0; r < 8; ++r) e[r] = bufB[s0 + i + r];
            const float* pr[8];
#pragma unroll
            for (int r = 0; r < 8; ++r) pr[r] = ctx + (e[r].y >> 7);
            float hi[8];
#pragma unroll
            for (int r = 0; r < 8; ++r) hi[r] = pr[r][lane];
#pragma unroll
            for (int r = 0; r < 8; ++r) a0 += __uint_as_float(e[r].x) * hi[r];
            if (lane < 16) {
                float lo[8];
#pragma unroll
                for (int r = 0; r < 8; ++r) lo[r] = pr[r][64 + lane];
#pragma unroll
                for (int r = 0; r < 8; ++r) a1 += __uint_as_float(e[r].x) * lo[r];
            }
        }
        sacc[lane][c] = a0;
        if (lane < 16) sacc[64 + lane][c] = a1;
    }

    // slow path for bucket overflow (~20 sigma; correctness only)
    if (total > CAP) {
        for (int blk = 0; blk < NBLK; ++blk) {
            const int dstb = segofs[blk];
            const int n    = segcnt[blk];
            if (dstb + n <= CAP) continue;
            const uint2* sp = plist + (size_t)blk * EPB + ofsmat[(size_t)blk * NBUCKET + bucket];
            const int i0 = (CAP > dstb) ? (CAP - dstb) : 0;
            for (int i = i0; i < n; ++i) {
                const uint2 e = sp[i];
                const int c = (int)(e.y & 127u);
                if ((c & 15) == wv) {
                    const float* pb = ctx + (e.y >> 7);
                    const float dep = __uint_as_float(e.x);
                    sacc[lane][c] += dep * pb[lane];
                    if (lane < 16) sacc[64 + lane][c] += dep * pb[64 + lane];
                }
            }
        }
    }
    __syncthreads();

    // epilogue: full 64B line writes to (B,C,H,W)
    const int b  = bucket >> 7;
    const int tl = bucket & 127;
    const int tr = tl >> 3;
    const int tc = tl & 7;
    const int c0  = tid >> 4;
    const int col = tid & 15;
#pragma unroll
    for (int cc = c0; cc < CTX; cc += 64) {
#pragma unroll
        for (int r = 0; r < 8; ++r) {
            out[((size_t)(b * CTX + cc)) * BEVHW + (tr * 8 + r) * 128 + tc * 16 + col]
                = sacc[cc][r * 16 + col];
        }
    }
}

extern "C" void kernel_launch(void* const* d_in, const int* in_sizes, int n_in,
                              void* d_out, int out_size, void* d_ws, size_t ws_size,
                              hipStream_t stream)
{
    const float* img  = (const float*)d_in[0];
    const float* w    = (const float*)d_in[4];
    const float* bias = (const float*)d_in[5];
    const int*   geom = (const int*)d_in[6];
    float*       out  = (float*)d_out;

    float* ws     = (float*)d_ws;
    float* xdepth = ws + XDEPTH_OFF;
    float* ctx    = ws + CTX_OFF;
    int*   cntmat = (int*)(ws + CNTMAT_OFF);
    int*   ofsmat = (int*)(ws + OFSMAT_OFF);
    uint2* plist  = (uint2*)(ws + PLIST_OFF);

    // 1. GEMM + bias -> depth logits (bn,d,pix) / transposed context (bn,pix,c)
    {
        dim3 grid(11, 3, BNPAIR);   // 64-pixel tiles (704 = 11*64 exact)
        gemm_kernel<<<grid, 256, 0, stream>>>(img, w, bias, xdepth, ctx);
    }
    // 2. fused softmax + deterministic block-local counting sort (no atomics)
    fill_kernel<<<NBLK, 256, 0, stream>>>(xdepth, geom, plist, cntmat, ofsmat);

    // 3. fused cell-sort + gather per bucket, coalesced (B,C,H,W) writes
    gather_kernel<<<NBUCKET, 1024, 0, stream>>>(plist, cntmat, ofsmat, ctx, out);
}